// Round 3
// baseline (4668.103 us; speedup 1.0000x reference)
//
#include <hip/hip_runtime.h>

#define N_USER 50000
#define N_ITEM 30000
#define DIM    64
#define NTOT   80000
#define NNZ_UI 1000000
#define NNZ_R  800000
#define NNZ_II 300000
#define IMG_F  512
#define TXT_F  384

// ---------------- cat0 = [item_emb; user_emb] ----------------
__global__ void k_cat0(const float* __restrict__ item, const float* __restrict__ user,
                       float* __restrict__ o1){
    int i = blockIdx.x * 256 + threadIdx.x;        // over NTOT*DIM (exact)
    const int ITEMS = N_ITEM * DIM;
    o1[i] = (i < ITEMS) ? item[i] : user[i - ITEMS];
}

// ---------------- edge-parallel SpMM: y[rows[e]] += vals[e]*x[cols[e]] ----------------
// x f32 [*,64], y f32 pre-zeroed. 16 lanes/edge, float4 per lane.
__global__ void k_spmm(const int* __restrict__ rows, const int* __restrict__ cols,
                       const float* __restrict__ vals,
                       const float* __restrict__ x, float* __restrict__ y, int nnz){
    int t = blockIdx.x * 256 + threadIdx.x;
    int e = t >> 4;
    if (e >= nnz) return;
    int l = (t & 15) << 2;
    float v = vals[e];
    long c = cols[e], r = rows[e];
    const float4 xv = *reinterpret_cast<const float4*>(x + (c << 6) + l);
    float* yp = y + (r << 6) + l;
    atomicAdd(yp + 0, v * xv.x);
    atomicAdd(yp + 1, v * xv.y);
    atomicAdd(yp + 2, v * xv.z);
    atomicAdd(yp + 3, v * xv.w);
}

// ---------------- content = (cat0+cat1+cat2)/3 ----------------
__global__ void k_content(const float* __restrict__ a, const float* __restrict__ b,
                          const float* __restrict__ c, float* __restrict__ o0){
    int i = blockIdx.x * 256 + threadIdx.x;
    o0[i] = (a[i] + b[i] + c[i]) * (1.0f / 3.0f);
}

// ---------------- projection: leaky(BN(X @ W + b)) ----------------
// X [M,K] f32, W [K,64] f32. 8 rows/block, 512 threads.
template<int K>
__global__ __launch_bounds__(512) void k_proj(const float* __restrict__ X,
        const float* __restrict__ W, const float* __restrict__ b,
        const float* __restrict__ g, const float* __restrict__ beta,
        float* __restrict__ out){
    __shared__ float xs[8 * K];
    const int t = threadIdx.x;
    const int row0 = blockIdx.x * 8;
    const float4* src4 = reinterpret_cast<const float4*>(X + (long)row0 * K);
    float4* xs4 = reinterpret_cast<float4*>(xs);
#pragma unroll
    for (int i = t; i < 2 * K; i += 512) xs4[i] = src4[i];
    __syncthreads();
    const int r = t >> 6, c = t & 63;
    const float* xr = xs + r * K;
    float acc = 0.f;
#pragma unroll 8
    for (int k = 0; k < K; ++k) acc = fmaf(xr[k], W[k * 64 + c], acc);
    float h = acc + b[c];
    h = h * (g[c] * 0.99999500003749943f) + beta[c];   // g / sqrt(1 + 1e-5)
    out[(long)(row0 + r) * 64 + c] = (h >= 0.f) ? h : 0.01f * h;
}

// ---------------- gate: it = item_emb * sigmoid(feat @ Wg + bg) ----------------
__global__ __launch_bounds__(512) void k_gate(const float* __restrict__ feat,
        const float* __restrict__ Wg, const float* __restrict__ bg,
        const float* __restrict__ item, float* __restrict__ it){
    __shared__ float fs[8][64];
    const int t = threadIdx.x;
    const int row0 = blockIdx.x * 8;
    fs[t >> 6][t & 63] = feat[(long)row0 * 64 + t];
    __syncthreads();
    const int r = t >> 6, c = t & 63;
    float acc = 0.f;
#pragma unroll
    for (int k = 0; k < 64; ++k) acc = fmaf(fs[r][k], Wg[k * 64 + c], acc);
    acc += bg[c];
    float sg = 1.f / (1.f + __expf(-acc));
    long idx = (long)(row0 + r) * 64 + c;
    it[idx] = item[idx] * sg;
}

// ---------------- ui = [us; it] ----------------
__global__ void k_cat_ui(const float* __restrict__ us, const float* __restrict__ it,
                         float* __restrict__ ui){
    int i = blockIdx.x * 256 + threadIdx.x;
    const int US = N_USER * DIM;
    ui[i] = (i < US) ? us[i] : it[i - US];
}

// ---------------- attention fusion; reads o1/o2, rewrites o1/o2/o3 in place ----------------
__global__ __launch_bounds__(256) void k_fuse(const float* __restrict__ img,
        const float* __restrict__ txt, const float* __restrict__ W1,
        const float* __restrict__ b1, const float* __restrict__ w2,
        float* __restrict__ out){
    __shared__ float si[4][64], st[4][64];
    const int t = threadIdx.x;
    const int w = t >> 6, c = t & 63;
    const long row = (long)blockIdx.x * 4 + w;
    float ie = img[row * 64 + c];
    float te = txt[row * 64 + c];
    si[w][c] = ie;  st[w][c] = te;
    __syncthreads();
    float ai = 0.f, at = 0.f;
#pragma unroll
    for (int k = 0; k < 64; ++k){
        float wv = W1[k * 64 + c];
        ai = fmaf(si[w][k], wv, ai);
        at = fmaf(st[w][k], wv, at);
    }
    float bb = b1[c];
    float hi = ai + bb; hi = (hi >= 0.f) ? hi : 0.01f * hi;
    float ht = at + bb; ht = (ht >= 0.f) ? ht : 0.01f * ht;
    float wc = w2[c];
    float pi = hi * wc, pt = ht * wc;
#pragma unroll
    for (int m = 1; m < 64; m <<= 1){
        pi += __shfl_xor(pi, m, 64);
        pt += __shfl_xor(pt, m, 64);
    }
    float mx = fmaxf(pi, pt);
    float ei = __expf(pi - mx), et = __expf(pt - mx);
    float inv = 1.f / (ei + et);
    float wi = ei * inv, wt = et * inv;
    float common = wi * ie + wt * te;
    const long NTD = (long)NTOT * DIM;
    long o = row * 64 + c;
    out[NTD + o]     = ie - common;
    out[2 * NTD + o] = te - common;
    out[3 * NTD + o] = common;
}

extern "C" void kernel_launch(void* const* d_in, const int* in_sizes, int n_in,
                              void* d_out, int out_size, void* d_ws, size_t ws_size,
                              hipStream_t stream){
    const float* user_emb  = (const float*)d_in[0];
    const float* item_emb  = (const float*)d_in[1];
    const float* image_emb = (const float*)d_in[2];
    const float* text_emb  = (const float*)d_in[3];
    const float* W_img = (const float*)d_in[4];
    const float* b_img = (const float*)d_in[5];
    const float* g_img = (const float*)d_in[6];
    const float* be_img= (const float*)d_in[7];
    const float* W_txt = (const float*)d_in[8];
    const float* b_txt = (const float*)d_in[9];
    const float* g_txt = (const float*)d_in[10];
    const float* be_txt= (const float*)d_in[11];
    const float* W_gi  = (const float*)d_in[12];
    const float* b_gi  = (const float*)d_in[13];
    const float* W_gt  = (const float*)d_in[14];
    const float* b_gt  = (const float*)d_in[15];
    const float* W_c1  = (const float*)d_in[16];
    const float* b_c1  = (const float*)d_in[17];
    const float* w_c2  = (const float*)d_in[18];
    const float* ui_vals = (const float*)d_in[19];
    const float* R_vals  = (const float*)d_in[20];
    const float* ii_iv   = (const float*)d_in[21];
    const float* ii_tv   = (const float*)d_in[22];
    const int* ui_rows = (const int*)d_in[23];
    const int* ui_cols = (const int*)d_in[24];
    const int* R_rows  = (const int*)d_in[25];
    const int* R_cols  = (const int*)d_in[26];
    const int* ii_ir   = (const int*)d_in[27];
    const int* ii_ic   = (const int*)d_in[28];
    const int* ii_tr   = (const int*)d_in[29];
    const int* ii_tc   = (const int*)d_in[30];

    const long ND = (long)NTOT * DIM;    // 5,120,000
    const long ID = (long)N_ITEM * DIM;  // 1,920,000
    const long UD = (long)N_USER * DIM;  // 3,200,000

    float* out = (float*)d_out;
    float* o0 = out;
    float* o1 = out + ND;
    float* o2 = out + 2 * ND;
    float* o3 = out + 3 * ND;

    // ---- workspace: P, Q (ID f32 each), U (UD f32) = 28.16 MB ----
    float* P = (float*)d_ws;
    float* Q = P + ID;
    float* U = Q + ID;

    // ---- content branch: cat0(o1) -> hop1(o2) -> hop2(o3) -> content(o0) ----
    k_cat0<<<ND / 256, 256, 0, stream>>>(item_emb, user_emb, o1);
    hipMemsetAsync(o2, 0, ND * sizeof(float), stream);
    k_spmm<<<NNZ_UI * 16 / 256, 256, 0, stream>>>(ui_rows, ui_cols, ui_vals, o1, o2, NNZ_UI);
    hipMemsetAsync(o3, 0, ND * sizeof(float), stream);
    k_spmm<<<NNZ_UI * 16 / 256, 256, 0, stream>>>(ui_rows, ui_cols, ui_vals, o2, o3, NNZ_UI);
    k_content<<<ND / 256, 256, 0, stream>>>(o1, o2, o3, o0);

    // ---- image branch -> o1 ----
    k_proj<IMG_F><<<N_ITEM / 8, 512, 0, stream>>>(image_emb, W_img, b_img, g_img, be_img, Q);
    k_gate<<<N_ITEM / 8, 512, 0, stream>>>(Q, W_gi, b_gi, item_emb, P);
    hipMemsetAsync(Q, 0, ID * sizeof(float), stream);
    k_spmm<<<NNZ_II * 16 / 256, 256, 0, stream>>>(ii_ir, ii_ic, ii_iv, P, Q, NNZ_II);
    hipMemsetAsync(P, 0, ID * sizeof(float), stream);
    k_spmm<<<NNZ_II * 16 / 256, 256, 0, stream>>>(ii_ir, ii_ic, ii_iv, Q, P, NNZ_II);
    hipMemsetAsync(U, 0, UD * sizeof(float), stream);
    k_spmm<<<NNZ_R * 16 / 256, 256, 0, stream>>>(R_rows, R_cols, R_vals, P, U, NNZ_R);
    k_cat_ui<<<ND / 256, 256, 0, stream>>>(U, P, o1);

    // ---- text branch -> o2 ----
    k_proj<TXT_F><<<N_ITEM / 8, 512, 0, stream>>>(text_emb, W_txt, b_txt, g_txt, be_txt, Q);
    k_gate<<<N_ITEM / 8, 512, 0, stream>>>(Q, W_gt, b_gt, item_emb, P);
    hipMemsetAsync(Q, 0, ID * sizeof(float), stream);
    k_spmm<<<NNZ_II * 16 / 256, 256, 0, stream>>>(ii_tr, ii_tc, ii_tv, P, Q, NNZ_II);
    hipMemsetAsync(P, 0, ID * sizeof(float), stream);
    k_spmm<<<NNZ_II * 16 / 256, 256, 0, stream>>>(ii_tr, ii_tc, ii_tv, Q, P, NNZ_II);
    hipMemsetAsync(U, 0, UD * sizeof(float), stream);
    k_spmm<<<NNZ_R * 16 / 256, 256, 0, stream>>>(R_rows, R_cols, R_vals, P, U, NNZ_R);
    k_cat_ui<<<ND / 256, 256, 0, stream>>>(U, P, o2);

    // ---- fusion epilogue (in-place on o1/o2, writes o3) ----
    k_fuse<<<NTOT / 4, 256, 0, stream>>>(o1, o2, W_c1, b_c1, w_c2, out);
}

// Round 4
// 1433.408 us; speedup vs baseline: 3.2566x; 3.2566x over previous
//
#include <hip/hip_runtime.h>

#define N_USER 50000
#define N_ITEM 30000
#define DIM    64
#define NTOT   80000
#define NNZ_UI 1000000
#define NNZ_R  800000
#define NNZ_II 300000
#define IMG_F  512
#define TXT_F  384

// ---------------- cat0 = [item_emb; user_emb] ----------------
__global__ void k_cat0(const float* __restrict__ item, const float* __restrict__ user,
                       float* __restrict__ o1){
    int i = blockIdx.x * 256 + threadIdx.x;        // over NTOT*DIM (exact)
    const int ITEMS = N_ITEM * DIM;
    o1[i] = (i < ITEMS) ? item[i] : user[i - ITEMS];
}

// ---------------- CSR build: histogram ----------------
__global__ void k_hist(const int* __restrict__ rows, int* __restrict__ cnt, int nnz){
    int i = blockIdx.x * 256 + threadIdx.x;
    if (i < nnz) atomicAdd(&cnt[rows[i]], 1);
}

// ---------------- CSR build: single-block exclusive scan ----------------
// cnt_head: in = counts, out = head (copy of exclusive offsets). off[0..n] = offsets.
__global__ __launch_bounds__(1024) void k_scan(int* __restrict__ cnt_head,
                                               int* __restrict__ off, int n){
    __shared__ int ssum[1024];
    const int t = threadIdx.x;
    const int chunk = (n + 1023) >> 10;
    const int lo = t * chunk;
    const int hi = min(lo + chunk, n);
    int s = 0;
    for (int i = lo; i < hi; ++i) s += cnt_head[i];
    ssum[t] = s;
    __syncthreads();
    for (int d = 1; d < 1024; d <<= 1){
        int u = (t >= d) ? ssum[t - d] : 0;
        __syncthreads();
        ssum[t] += u;
        __syncthreads();
    }
    int run = ssum[t] - s;      // exclusive prefix for this thread's chunk
    for (int i = lo; i < hi; ++i){
        int c = cnt_head[i];
        off[i] = run;
        cnt_head[i] = run;      // head init (same thread read-then-write: safe)
        run += c;
    }
    if (t == 1023) off[n] = run;
}

// ---------------- CSR build: scatter edges into slots ----------------
__global__ void k_fill(const int* __restrict__ rows, const int* __restrict__ cols,
                       const float* __restrict__ vals,
                       int* __restrict__ head, int2* __restrict__ csr, int nnz){
    int i = blockIdx.x * 256 + threadIdx.x;
    if (i >= nnz) return;
    int p = atomicAdd(&head[rows[i]], 1);
    csr[p] = make_int2(cols[i], __float_as_int(vals[i]));
}

// ---------------- pull-SpMM: y[r] = sum_e val*x[col], one row per 16 lanes ----------------
__global__ void k_pull(const int* __restrict__ off, const int2* __restrict__ csr,
                       const float* __restrict__ x, float* __restrict__ y, int nrows){
    int t = blockIdx.x * 256 + threadIdx.x;
    int r = t >> 4;
    if (r >= nrows) return;
    int l = (t & 15) << 2;
    int s = off[r], e = off[r + 1];
    float4 acc = {0.f, 0.f, 0.f, 0.f};
    for (int j = s; j < e; ++j){
        int2 ed = csr[j];                           // broadcast across the 16 lanes
        float v = __int_as_float(ed.y);
        const float4 xv = *reinterpret_cast<const float4*>(x + ((long)ed.x << 6) + l);
        acc.x = fmaf(v, xv.x, acc.x);
        acc.y = fmaf(v, xv.y, acc.y);
        acc.z = fmaf(v, xv.z, acc.z);
        acc.w = fmaf(v, xv.w, acc.w);
    }
    *reinterpret_cast<float4*>(y + ((long)r << 6) + l) = acc;
}

// ---------------- content = (cat0+cat1+cat2)/3 ----------------
__global__ void k_content(const float* __restrict__ a, const float* __restrict__ b,
                          const float* __restrict__ c, float* __restrict__ o0){
    int i = blockIdx.x * 256 + threadIdx.x;
    o0[i] = (a[i] + b[i] + c[i]) * (1.0f / 3.0f);
}

// ---------------- projection: leaky(BN(X @ W + b)) ----------------
template<int K>
__global__ __launch_bounds__(512) void k_proj(const float* __restrict__ X,
        const float* __restrict__ W, const float* __restrict__ b,
        const float* __restrict__ g, const float* __restrict__ beta,
        float* __restrict__ out){
    __shared__ float xs[8 * K];
    const int t = threadIdx.x;
    const int row0 = blockIdx.x * 8;
    const float4* src4 = reinterpret_cast<const float4*>(X + (long)row0 * K);
    float4* xs4 = reinterpret_cast<float4*>(xs);
#pragma unroll
    for (int i = t; i < 2 * K; i += 512) xs4[i] = src4[i];
    __syncthreads();
    const int r = t >> 6, c = t & 63;
    const float* xr = xs + r * K;
    float acc = 0.f;
#pragma unroll 8
    for (int k = 0; k < K; ++k) acc = fmaf(xr[k], W[k * 64 + c], acc);
    float h = acc + b[c];
    h = h * (g[c] * 0.99999500003749943f) + beta[c];   // g / sqrt(1 + 1e-5)
    out[(long)(row0 + r) * 64 + c] = (h >= 0.f) ? h : 0.01f * h;
}

// ---------------- gate: it = item_emb * sigmoid(feat @ Wg + bg) ----------------
__global__ __launch_bounds__(512) void k_gate(const float* __restrict__ feat,
        const float* __restrict__ Wg, const float* __restrict__ bg,
        const float* __restrict__ item, float* __restrict__ it){
    __shared__ float fs[8][64];
    const int t = threadIdx.x;
    const int row0 = blockIdx.x * 8;
    fs[t >> 6][t & 63] = feat[(long)row0 * 64 + t];
    __syncthreads();
    const int r = t >> 6, c = t & 63;
    float acc = 0.f;
#pragma unroll
    for (int k = 0; k < 64; ++k) acc = fmaf(fs[r][k], Wg[k * 64 + c], acc);
    acc += bg[c];
    float sg = 1.f / (1.f + __expf(-acc));
    long idx = (long)(row0 + r) * 64 + c;
    it[idx] = item[idx] * sg;
}

// ---------------- copy ID elements (item part into ui tail) ----------------
__global__ void k_copy(const float* __restrict__ s, float* __restrict__ d){
    int i = blockIdx.x * 256 + threadIdx.x;
    d[i] = s[i];
}

// ---------------- attention fusion; reads o1/o2, rewrites o1/o2/o3 in place ----------------
__global__ __launch_bounds__(256) void k_fuse(const float* __restrict__ img,
        const float* __restrict__ txt, const float* __restrict__ W1,
        const float* __restrict__ b1, const float* __restrict__ w2,
        float* __restrict__ out){
    __shared__ float si[4][64], st[4][64];
    const int t = threadIdx.x;
    const int w = t >> 6, c = t & 63;
    const long row = (long)blockIdx.x * 4 + w;
    float ie = img[row * 64 + c];
    float te = txt[row * 64 + c];
    si[w][c] = ie;  st[w][c] = te;
    __syncthreads();
    float ai = 0.f, at = 0.f;
#pragma unroll
    for (int k = 0; k < 64; ++k){
        float wv = W1[k * 64 + c];
        ai = fmaf(si[w][k], wv, ai);
        at = fmaf(st[w][k], wv, at);
    }
    float bb = b1[c];
    float hi = ai + bb; hi = (hi >= 0.f) ? hi : 0.01f * hi;
    float ht = at + bb; ht = (ht >= 0.f) ? ht : 0.01f * ht;
    float wc = w2[c];
    float pi = hi * wc, pt = ht * wc;
#pragma unroll
    for (int m = 1; m < 64; m <<= 1){
        pi += __shfl_xor(pi, m, 64);
        pt += __shfl_xor(pt, m, 64);
    }
    float mx = fmaxf(pi, pt);
    float ei = __expf(pi - mx), et = __expf(pt - mx);
    float inv = 1.f / (ei + et);
    float wi = ei * inv, wt = et * inv;
    float common = wi * ie + wt * te;
    const long NTD = (long)NTOT * DIM;
    long o = row * 64 + c;
    out[NTD + o]     = ie - common;
    out[2 * NTD + o] = te - common;
    out[3 * NTD + o] = common;
}

extern "C" void kernel_launch(void* const* d_in, const int* in_sizes, int n_in,
                              void* d_out, int out_size, void* d_ws, size_t ws_size,
                              hipStream_t stream){
    const float* user_emb  = (const float*)d_in[0];
    const float* item_emb  = (const float*)d_in[1];
    const float* image_emb = (const float*)d_in[2];
    const float* text_emb  = (const float*)d_in[3];
    const float* W_img = (const float*)d_in[4];
    const float* b_img = (const float*)d_in[5];
    const float* g_img = (const float*)d_in[6];
    const float* be_img= (const float*)d_in[7];
    const float* W_txt = (const float*)d_in[8];
    const float* b_txt = (const float*)d_in[9];
    const float* g_txt = (const float*)d_in[10];
    const float* be_txt= (const float*)d_in[11];
    const float* W_gi  = (const float*)d_in[12];
    const float* b_gi  = (const float*)d_in[13];
    const float* W_gt  = (const float*)d_in[14];
    const float* b_gt  = (const float*)d_in[15];
    const float* W_c1  = (const float*)d_in[16];
    const float* b_c1  = (const float*)d_in[17];
    const float* w_c2  = (const float*)d_in[18];
    const float* ui_vals = (const float*)d_in[19];
    const float* R_vals  = (const float*)d_in[20];
    const float* ii_iv   = (const float*)d_in[21];
    const float* ii_tv   = (const float*)d_in[22];
    const int* ui_rows = (const int*)d_in[23];
    const int* ui_cols = (const int*)d_in[24];
    const int* R_rows  = (const int*)d_in[25];
    const int* R_cols  = (const int*)d_in[26];
    const int* ii_ir   = (const int*)d_in[27];
    const int* ii_ic   = (const int*)d_in[28];
    const int* ii_tr   = (const int*)d_in[29];
    const int* ii_tc   = (const int*)d_in[30];

    const long ND = (long)NTOT * DIM;    // 5,120,000
    const long ID = (long)N_ITEM * DIM;  // 1,920,000
    const long UD = (long)N_USER * DIM;  // 3,200,000

    float* out = (float*)d_out;
    float* o0 = out;
    float* o1 = out + ND;
    float* o2 = out + 2 * ND;
    float* o3 = out + 3 * ND;

    // P/Q scratch live in o3 (free until k_fuse): 2*ID <= ND
    float* P = o3;
    float* Q = o3 + ID;

    // ---- workspace: CSR buffers (~15.5 MB) ----
    int2* csrA = (int2*)d_ws;            // 1M   (UI; reused for II at 300K)
    int2* csrR = csrA + NNZ_UI;          // 800K
    int*  offA = (int*)(csrR + NNZ_R);   // NTOT+1
    int*  headA= offA + NTOT + 1;        // NTOT
    int*  offR = headA + NTOT;           // N_USER+1
    int*  headR= offR + N_USER + 1;      // N_USER

    const int GE_UI = (NNZ_UI + 255) / 256;
    const int GE_R  = (NNZ_R  + 255) / 256;
    const int GE_II = (NNZ_II + 255) / 256;

    // ---- build R CSR (used by both branches) ----
    hipMemsetAsync(headR, 0, N_USER * sizeof(int), stream);
    k_hist<<<GE_R, 256, 0, stream>>>(R_rows, headR, NNZ_R);
    k_scan<<<1, 1024, 0, stream>>>(headR, offR, N_USER);
    k_fill<<<GE_R, 256, 0, stream>>>(R_rows, R_cols, R_vals, headR, csrR, NNZ_R);

    // ---- build UI CSR + content branch ----
    hipMemsetAsync(headA, 0, NTOT * sizeof(int), stream);
    k_hist<<<GE_UI, 256, 0, stream>>>(ui_rows, headA, NNZ_UI);
    k_scan<<<1, 1024, 0, stream>>>(headA, offA, NTOT);
    k_fill<<<GE_UI, 256, 0, stream>>>(ui_rows, ui_cols, ui_vals, headA, csrA, NNZ_UI);

    k_cat0<<<ND / 256, 256, 0, stream>>>(item_emb, user_emb, o1);
    k_pull<<<NTOT / 16, 256, 0, stream>>>(offA, csrA, o1, o2, NTOT);
    k_pull<<<NTOT / 16, 256, 0, stream>>>(offA, csrA, o2, o3, NTOT);
    k_content<<<ND / 256, 256, 0, stream>>>(o1, o2, o3, o0);
    // o3 (P/Q scratch) is free again from here

    // ---- image branch -> o1 ----
    hipMemsetAsync(headA, 0, N_ITEM * sizeof(int), stream);
    k_hist<<<GE_II, 256, 0, stream>>>(ii_ir, headA, NNZ_II);
    k_scan<<<1, 1024, 0, stream>>>(headA, offA, N_ITEM);
    k_fill<<<GE_II, 256, 0, stream>>>(ii_ir, ii_ic, ii_iv, headA, csrA, NNZ_II);

    k_proj<IMG_F><<<N_ITEM / 8, 512, 0, stream>>>(image_emb, W_img, b_img, g_img, be_img, Q);
    k_gate<<<N_ITEM / 8, 512, 0, stream>>>(Q, W_gi, b_gi, item_emb, P);
    k_pull<<<N_ITEM / 16, 256, 0, stream>>>(offA, csrA, P, Q, N_ITEM);
    k_pull<<<N_ITEM / 16, 256, 0, stream>>>(offA, csrA, Q, P, N_ITEM);
    k_pull<<<N_USER / 16, 256, 0, stream>>>(offR, csrR, P, o1, N_USER);
    k_copy<<<ID / 256, 256, 0, stream>>>(P, o1 + UD);

    // ---- text branch -> o2 ----
    hipMemsetAsync(headA, 0, N_ITEM * sizeof(int), stream);
    k_hist<<<GE_II, 256, 0, stream>>>(ii_tr, headA, NNZ_II);
    k_scan<<<1, 1024, 0, stream>>>(headA, offA, N_ITEM);
    k_fill<<<GE_II, 256, 0, stream>>>(ii_tr, ii_tc, ii_tv, headA, csrA, NNZ_II);

    k_proj<TXT_F><<<N_ITEM / 8, 512, 0, stream>>>(text_emb, W_txt, b_txt, g_txt, be_txt, Q);
    k_gate<<<N_ITEM / 8, 512, 0, stream>>>(Q, W_gt, b_gt, item_emb, P);
    k_pull<<<N_ITEM / 16, 256, 0, stream>>>(offA, csrA, P, Q, N_ITEM);
    k_pull<<<N_ITEM / 16, 256, 0, stream>>>(offA, csrA, Q, P, N_ITEM);
    k_pull<<<N_USER / 16, 256, 0, stream>>>(offR, csrR, P, o2, N_USER);
    k_copy<<<ID / 256, 256, 0, stream>>>(P, o2 + UD);

    // ---- fusion epilogue (in-place on o1/o2, writes o3) ----
    k_fuse<<<NTOT / 4, 256, 0, stream>>>(o1, o2, W_c1, b_c1, w_c2, out);
}

// Round 5
// 1039.488 us; speedup vs baseline: 4.4908x; 1.3790x over previous
//
#include <hip/hip_runtime.h>

#define N_USER 50000
#define N_ITEM 30000
#define DIM    64
#define NTOT   80000
#define NNZ_UI 1000000
#define NNZ_R  800000
#define NNZ_II 300000
#define IMG_F  512
#define TXT_F  384

#define NROWS_ALL 190000            // NTOT + N_USER + N_ITEM + N_ITEM
#define NNZ_ALL   2400000           // NNZ_UI + NNZ_R + 2*NNZ_II
#define BASE_R    NTOT              // 80000
#define BASE_II   (NTOT + N_USER)   // 130000
#define BASE_IT   (NTOT + N_USER + N_ITEM) // 160000
#define SCAN_T    2048
#define NBLK_SCAN ((NROWS_ALL + SCAN_T - 1) / SCAN_T)   // 93

// ---------------- cat0 = [item_emb; user_emb] ----------------
__global__ void k_cat0(const float* __restrict__ item, const float* __restrict__ user,
                       float* __restrict__ o1){
    int i = blockIdx.x * 256 + threadIdx.x;
    const int ITEMS = N_ITEM * DIM;
    o1[i] = (i < ITEMS) ? item[i] : user[i - ITEMS];
}

// ---------------- fused histogram over all 4 edge lists ----------------
__global__ void k_hist4(const int* __restrict__ r0, const int* __restrict__ r1,
                        const int* __restrict__ r2, const int* __restrict__ r3,
                        int* __restrict__ cnt){
    int i = blockIdx.x * 256 + threadIdx.x;     // over NNZ_ALL (exact)
    int gr;
    if (i < NNZ_UI)                  gr = r0[i];
    else if (i < NNZ_UI + NNZ_R)     gr = BASE_R  + r1[i - NNZ_UI];
    else if (i < NNZ_UI + NNZ_R + NNZ_II) gr = BASE_II + r2[i - NNZ_UI - NNZ_R];
    else                             gr = BASE_IT + r3[i - NNZ_UI - NNZ_R - NNZ_II];
    atomicAdd(&cnt[gr], 1);
}

// ---------------- scan stage 1: per-block local exclusive scan ----------------
__global__ __launch_bounds__(256) void k_scan1(const int* __restrict__ cnt,
        int* __restrict__ off, int* __restrict__ bsum, int n){
    __shared__ int wsum[4];
    const int t = threadIdx.x;
    const int base = blockIdx.x * SCAN_T + t * 8;
    int v[8];
    if (base + 8 <= n){
        const int4* p = reinterpret_cast<const int4*>(cnt + base);
        int4 a = p[0], b = p[1];
        v[0]=a.x; v[1]=a.y; v[2]=a.z; v[3]=a.w; v[4]=b.x; v[5]=b.y; v[6]=b.z; v[7]=b.w;
    } else {
#pragma unroll
        for (int i = 0; i < 8; ++i) v[i] = (base + i < n) ? cnt[base + i] : 0;
    }
    int s = 0;
#pragma unroll
    for (int i = 0; i < 8; ++i) s += v[i];
    const int lane = t & 63, wid = t >> 6;
    int incl = s;
#pragma unroll
    for (int d = 1; d < 64; d <<= 1){
        int u = __shfl_up(incl, d, 64);
        if (lane >= d) incl += u;
    }
    if (lane == 63) wsum[wid] = incl;
    __syncthreads();
    int woff = 0;
    for (int w = 0; w < wid; ++w) woff += wsum[w];
    int run = woff + incl - s;                  // thread exclusive prefix
    if (base + 8 <= n){
        int o[8];
#pragma unroll
        for (int i = 0; i < 8; ++i){ o[i] = run; run += v[i]; }
        int4* q = reinterpret_cast<int4*>(off + base);
        q[0] = make_int4(o[0], o[1], o[2], o[3]);
        q[1] = make_int4(o[4], o[5], o[6], o[7]);
    } else {
        for (int i = 0; i < 8; ++i){ if (base + i < n) off[base + i] = run; run += v[i]; }
    }
    if (t == 255) bsum[blockIdx.x] = wsum[0] + wsum[1] + wsum[2] + wsum[3];
}

// ---------------- scan stage 2: scan the block sums (nb <= 128) ----------------
__global__ __launch_bounds__(128) void k_scan2(int* __restrict__ bsum,
        int* __restrict__ off, int nb, int n){
    __shared__ int sh[128];
    const int t = threadIdx.x;
    int v = (t < nb) ? bsum[t] : 0;
    sh[t] = v;
    __syncthreads();
    for (int d = 1; d < 128; d <<= 1){
        int u = (t >= d) ? sh[t - d] : 0;
        __syncthreads();
        sh[t] += u;
        __syncthreads();
    }
    if (t < nb) bsum[t] = sh[t] - v;            // exclusive block prefix
    if (t == nb - 1) off[n] = sh[t];            // grand total
}

// ---------------- scan stage 3: add block prefixes; init head ----------------
__global__ void k_scan3(int* __restrict__ off, const int* __restrict__ bsum,
                        int* __restrict__ head, int n){
    int i = blockIdx.x * 256 + threadIdx.x;
    if (i >= n) return;
    int o = off[i] + bsum[i >> 11];             // SCAN_T == 2048
    off[i] = o;
    head[i] = o;
}

// ---------------- fused fill over all 4 edge lists ----------------
__global__ void k_fill4(const int* __restrict__ r0, const int* __restrict__ c0, const float* __restrict__ v0,
                        const int* __restrict__ r1, const int* __restrict__ c1, const float* __restrict__ v1,
                        const int* __restrict__ r2, const int* __restrict__ c2, const float* __restrict__ v2,
                        const int* __restrict__ r3, const int* __restrict__ c3, const float* __restrict__ v3,
                        int* __restrict__ head, int2* __restrict__ csr){
    int i = blockIdx.x * 256 + threadIdx.x;     // over NNZ_ALL (exact)
    int gr, col; float val;
    if (i < NNZ_UI){
        gr = r0[i]; col = c0[i]; val = v0[i];
    } else if (i < NNZ_UI + NNZ_R){
        int j = i - NNZ_UI;              gr = BASE_R  + r1[j]; col = c1[j]; val = v1[j];
    } else if (i < NNZ_UI + NNZ_R + NNZ_II){
        int j = i - NNZ_UI - NNZ_R;      gr = BASE_II + r2[j]; col = c2[j]; val = v2[j];
    } else {
        int j = i - NNZ_UI - NNZ_R - NNZ_II; gr = BASE_IT + r3[j]; col = c3[j]; val = v3[j];
    }
    int p = atomicAdd(&head[gr], 1);
    csr[p] = make_int2(col, __float_as_int(val));
}

// ---------------- pull-SpMM: y[r] = sum val*x[col], one row per 16 lanes ----------------
__global__ void k_pull(const int* __restrict__ off, const int2* __restrict__ csr,
                       const float* __restrict__ x, float* __restrict__ y, int nrows){
    int t = blockIdx.x * 256 + threadIdx.x;
    int r = t >> 4;
    if (r >= nrows) return;
    int l = (t & 15) << 2;
    int s = off[r], e = off[r + 1];
    float4 acc = {0.f, 0.f, 0.f, 0.f};
    for (int j = s; j < e; ++j){
        int2 ed = csr[j];
        float v = __int_as_float(ed.y);
        const float4 xv = *reinterpret_cast<const float4*>(x + ((long)ed.x << 6) + l);
        acc.x = fmaf(v, xv.x, acc.x);
        acc.y = fmaf(v, xv.y, acc.y);
        acc.z = fmaf(v, xv.z, acc.z);
        acc.w = fmaf(v, xv.w, acc.w);
    }
    *reinterpret_cast<float4*>(y + ((long)r << 6) + l) = acc;
}

// ---------------- content = (cat0+cat1+cat2)/3 ----------------
__global__ void k_content(const float* __restrict__ a, const float* __restrict__ b,
                          const float* __restrict__ c, float* __restrict__ o0){
    int i = blockIdx.x * 256 + threadIdx.x;
    o0[i] = (a[i] + b[i] + c[i]) * (1.0f / 3.0f);
}

// ---------------- projection: leaky(BN(X @ W + b)) ----------------
template<int K>
__global__ __launch_bounds__(512) void k_proj(const float* __restrict__ X,
        const float* __restrict__ W, const float* __restrict__ b,
        const float* __restrict__ g, const float* __restrict__ beta,
        float* __restrict__ out){
    __shared__ float xs[8 * K];
    const int t = threadIdx.x;
    const int row0 = blockIdx.x * 8;
    const float4* src4 = reinterpret_cast<const float4*>(X + (long)row0 * K);
    float4* xs4 = reinterpret_cast<float4*>(xs);
#pragma unroll
    for (int i = t; i < 2 * K; i += 512) xs4[i] = src4[i];
    __syncthreads();
    const int r = t >> 6, c = t & 63;
    const float* xr = xs + r * K;
    float acc = 0.f;
#pragma unroll 8
    for (int k = 0; k < K; ++k) acc = fmaf(xr[k], W[k * 64 + c], acc);
    float h = acc + b[c];
    h = h * (g[c] * 0.99999500003749943f) + beta[c];   // g / sqrt(1 + 1e-5)
    out[(long)(row0 + r) * 64 + c] = (h >= 0.f) ? h : 0.01f * h;
}

// ---------------- gate: it = item_emb * sigmoid(feat @ Wg + bg) ----------------
__global__ __launch_bounds__(512) void k_gate(const float* __restrict__ feat,
        const float* __restrict__ Wg, const float* __restrict__ bg,
        const float* __restrict__ item, float* __restrict__ it){
    __shared__ float fs[8][64];
    const int t = threadIdx.x;
    const int row0 = blockIdx.x * 8;
    fs[t >> 6][t & 63] = feat[(long)row0 * 64 + t];
    __syncthreads();
    const int r = t >> 6, c = t & 63;
    float acc = 0.f;
#pragma unroll
    for (int k = 0; k < 64; ++k) acc = fmaf(fs[r][k], Wg[k * 64 + c], acc);
    acc += bg[c];
    float sg = 1.f / (1.f + __expf(-acc));
    long idx = (long)(row0 + r) * 64 + c;
    it[idx] = item[idx] * sg;
}

// ---------------- copy ID elements ----------------
__global__ void k_copy(const float* __restrict__ s, float* __restrict__ d){
    int i = blockIdx.x * 256 + threadIdx.x;
    d[i] = s[i];
}

// ---------------- attention fusion; reads o1/o2, rewrites o1/o2/o3 in place ----------------
__global__ __launch_bounds__(256) void k_fuse(const float* __restrict__ img,
        const float* __restrict__ txt, const float* __restrict__ W1,
        const float* __restrict__ b1, const float* __restrict__ w2,
        float* __restrict__ out){
    __shared__ float si[4][64], st[4][64];
    const int t = threadIdx.x;
    const int w = t >> 6, c = t & 63;
    const long row = (long)blockIdx.x * 4 + w;
    float ie = img[row * 64 + c];
    float te = txt[row * 64 + c];
    si[w][c] = ie;  st[w][c] = te;
    __syncthreads();
    float ai = 0.f, at = 0.f;
#pragma unroll
    for (int k = 0; k < 64; ++k){
        float wv = W1[k * 64 + c];
        ai = fmaf(si[w][k], wv, ai);
        at = fmaf(st[w][k], wv, at);
    }
    float bb = b1[c];
    float hi = ai + bb; hi = (hi >= 0.f) ? hi : 0.01f * hi;
    float ht = at + bb; ht = (ht >= 0.f) ? ht : 0.01f * ht;
    float wc = w2[c];
    float pi = hi * wc, pt = ht * wc;
#pragma unroll
    for (int m = 1; m < 64; m <<= 1){
        pi += __shfl_xor(pi, m, 64);
        pt += __shfl_xor(pt, m, 64);
    }
    float mx = fmaxf(pi, pt);
    float ei = __expf(pi - mx), et = __expf(pt - mx);
    float inv = 1.f / (ei + et);
    float wi = ei * inv, wt = et * inv;
    float common = wi * ie + wt * te;
    const long NTD = (long)NTOT * DIM;
    long o = row * 64 + c;
    out[NTD + o]     = ie - common;
    out[2 * NTD + o] = te - common;
    out[3 * NTD + o] = common;
}

extern "C" void kernel_launch(void* const* d_in, const int* in_sizes, int n_in,
                              void* d_out, int out_size, void* d_ws, size_t ws_size,
                              hipStream_t stream){
    const float* user_emb  = (const float*)d_in[0];
    const float* item_emb  = (const float*)d_in[1];
    const float* image_emb = (const float*)d_in[2];
    const float* text_emb  = (const float*)d_in[3];
    const float* W_img = (const float*)d_in[4];
    const float* b_img = (const float*)d_in[5];
    const float* g_img = (const float*)d_in[6];
    const float* be_img= (const float*)d_in[7];
    const float* W_txt = (const float*)d_in[8];
    const float* b_txt = (const float*)d_in[9];
    const float* g_txt = (const float*)d_in[10];
    const float* be_txt= (const float*)d_in[11];
    const float* W_gi  = (const float*)d_in[12];
    const float* b_gi  = (const float*)d_in[13];
    const float* W_gt  = (const float*)d_in[14];
    const float* b_gt  = (const float*)d_in[15];
    const float* W_c1  = (const float*)d_in[16];
    const float* b_c1  = (const float*)d_in[17];
    const float* w_c2  = (const float*)d_in[18];
    const float* ui_vals = (const float*)d_in[19];
    const float* R_vals  = (const float*)d_in[20];
    const float* ii_iv   = (const float*)d_in[21];
    const float* ii_tv   = (const float*)d_in[22];
    const int* ui_rows = (const int*)d_in[23];
    const int* ui_cols = (const int*)d_in[24];
    const int* R_rows  = (const int*)d_in[25];
    const int* R_cols  = (const int*)d_in[26];
    const int* ii_ir   = (const int*)d_in[27];
    const int* ii_ic   = (const int*)d_in[28];
    const int* ii_tr   = (const int*)d_in[29];
    const int* ii_tc   = (const int*)d_in[30];

    const long ND = (long)NTOT * DIM;    // 5,120,000
    const long ID = (long)N_ITEM * DIM;  // 1,920,000
    const long UD = (long)N_USER * DIM;  // 3,200,000

    float* out = (float*)d_out;
    float* o0 = out;
    float* o1 = out + ND;
    float* o2 = out + 2 * ND;
    float* o3 = out + 3 * ND;

    // P/Q scratch live in o3 (free until k_fuse): 2*ID <= ND
    float* P = o3;
    float* Q = o3 + ID;

    // ---- workspace (~21.5 MB): combined CSR ----
    int2* csr  = (int2*)d_ws;                 // NNZ_ALL (19.2 MB, 16B-aligned)
    int*  cnt  = (int*)(csr + NNZ_ALL);       // NROWS_ALL   (offset 19.2e6, /16 ok)
    int*  off  = cnt + NROWS_ALL;             // NROWS_ALL+1 (760000 B later, /16 ok)
    int*  head = off + NROWS_ALL + 4;         // NROWS_ALL (+4 keeps 16B align)
    int*  bsum = head + NROWS_ALL;            // NBLK_SCAN

    // ---- build combined CSR (one hist, one scan, one fill) ----
    hipMemsetAsync(cnt, 0, NROWS_ALL * sizeof(int), stream);
    k_hist4<<<NNZ_ALL / 256, 256, 0, stream>>>(ui_rows, R_rows, ii_ir, ii_tr, cnt);
    k_scan1<<<NBLK_SCAN, 256, 0, stream>>>(cnt, off, bsum, NROWS_ALL);
    k_scan2<<<1, 128, 0, stream>>>(bsum, off, NBLK_SCAN, NROWS_ALL);
    k_scan3<<<(NROWS_ALL + 255) / 256, 256, 0, stream>>>(off, bsum, head, NROWS_ALL);
    k_fill4<<<NNZ_ALL / 256, 256, 0, stream>>>(
        ui_rows, ui_cols, ui_vals,  R_rows, R_cols, R_vals,
        ii_ir, ii_ic, ii_iv,        ii_tr, ii_tc, ii_tv,  head, csr);

    const int* offUI = off;
    const int* offR  = off + BASE_R;
    const int* offI2 = off + BASE_II;
    const int* offT2 = off + BASE_IT;

    // ---- content branch ----
    k_cat0<<<ND / 256, 256, 0, stream>>>(item_emb, user_emb, o1);
    k_pull<<<NTOT / 16, 256, 0, stream>>>(offUI, csr, o1, o2, NTOT);
    k_pull<<<NTOT / 16, 256, 0, stream>>>(offUI, csr, o2, o3, NTOT);
    k_content<<<ND / 256, 256, 0, stream>>>(o1, o2, o3, o0);
    // o3 (P/Q scratch) free again from here

    // ---- image branch -> o1 ----
    k_proj<IMG_F><<<N_ITEM / 8, 512, 0, stream>>>(image_emb, W_img, b_img, g_img, be_img, Q);
    k_gate<<<N_ITEM / 8, 512, 0, stream>>>(Q, W_gi, b_gi, item_emb, P);
    k_pull<<<N_ITEM / 16, 256, 0, stream>>>(offI2, csr, P, Q, N_ITEM);
    k_pull<<<N_ITEM / 16, 256, 0, stream>>>(offI2, csr, Q, P, N_ITEM);
    k_pull<<<N_USER / 16, 256, 0, stream>>>(offR, csr, P, o1, N_USER);
    k_copy<<<ID / 256, 256, 0, stream>>>(P, o1 + UD);

    // ---- text branch -> o2 ----
    k_proj<TXT_F><<<N_ITEM / 8, 512, 0, stream>>>(text_emb, W_txt, b_txt, g_txt, be_txt, Q);
    k_gate<<<N_ITEM / 8, 512, 0, stream>>>(Q, W_gt, b_gt, item_emb, P);
    k_pull<<<N_ITEM / 16, 256, 0, stream>>>(offT2, csr, P, Q, N_ITEM);
    k_pull<<<N_ITEM / 16, 256, 0, stream>>>(offT2, csr, Q, P, N_ITEM);
    k_pull<<<N_USER / 16, 256, 0, stream>>>(offR, csr, P, o2, N_USER);
    k_copy<<<ID / 256, 256, 0, stream>>>(P, o2 + UD);

    // ---- fusion epilogue (in-place on o1/o2, writes o3) ----
    k_fuse<<<NTOT / 4, 256, 0, stream>>>(o1, o2, W_c1, b_c1, w_c2, out);
}